// Round 3
// baseline (815.609 us; speedup 1.0000x reference)
//
#include <hip/hip_runtime.h>

// SketchDecoder: sequential 1000-step scan, 5-float carried state.
// Ref bug: hidden state never propagated -> W_hh unused, fg gate unused.
// Single block, 512 threads; weights in registers; eps (jax threefry) in LDS.
// RNG: JAX *partitionable* threefry (default since jax 0.5.0):
//   bits[i] = fold_in32(threefry2x32(key=(0,42), counter=(0, i)))  with fold = o0 ^ o1

typedef float v2f __attribute__((ext_vector_type(2)));

#define HH   2048
#define MAXS 1000
#define NT   512
#define NWAVE (NT / 64)

static __device__ __forceinline__ float exp2g(float x){ return __builtin_amdgcn_exp2f(x); }
static __device__ __forceinline__ float rcpg (float x){ return __builtin_amdgcn_rcpf(x); }
static __device__ __forceinline__ v2f exp2v(v2f x){ v2f r; r.x = exp2g(x.x); r.y = exp2g(x.y); return r; }
static __device__ __forceinline__ v2f rcpv (v2f x){ v2f r; r.x = rcpg(x.x); r.y = rcpg(x.y); return r; }

// sigmoid(x) where xs = log2(e)*x was pre-scaled into the weights
static __device__ __forceinline__ v2f sigm_s(v2f xs){ return rcpv(1.0f + exp2v(-xs)); }
// tanh(x) where xs = 2*log2(e)*x was pre-scaled
static __device__ __forceinline__ v2f tanh_s(v2f xs){ return 1.0f - 2.0f * rcpv(1.0f + exp2v(xs)); }

// ---- DPP wave64 sum: result valid in lane 63 (classic gfx9 pattern) ----
template<int CTRL>
static __device__ __forceinline__ float dpp_add(float x){
  int t = __builtin_amdgcn_update_dpp(0, __builtin_bit_cast(int, x), CTRL, 0xF, 0xF, true);
  return x + __builtin_bit_cast(float, t);
}
static __device__ __forceinline__ float wave_sum63(float x){
  x = dpp_add<0x111>(x);  // row_shr:1
  x = dpp_add<0x112>(x);  // row_shr:2
  x = dpp_add<0x114>(x);  // row_shr:4
  x = dpp_add<0x118>(x);  // row_shr:8  -> lane15/31/47/63 hold row sums
  x = dpp_add<0x142>(x);  // row_bcast:15
  x = dpp_add<0x143>(x);  // row_bcast:31 -> lane 63 holds wave total
  return x;
}
static __device__ __forceinline__ float rdfl(float x){
  return __builtin_bit_cast(float, __builtin_amdgcn_readfirstlane(__builtin_bit_cast(int, x)));
}

// ---- JAX threefry2x32 with key(42) -> key words (0, 42) ----
static __device__ __forceinline__ void tf_round(unsigned &x0, unsigned &x1, const int r){
  x0 += x1;
  x1 = (x1 << r) | (x1 >> (32 - r));
  x1 ^= x0;
}
static __device__ void threefry2x32_0_42(unsigned c0, unsigned c1, unsigned &o0, unsigned &o1){
  const unsigned k0 = 0u, k1 = 42u;
  const unsigned k2 = 0x1BD11BDAu ^ k0 ^ k1;
  unsigned x0 = c0 + k0, x1 = c1 + k1;
  tf_round(x0,x1,13); tf_round(x0,x1,15); tf_round(x0,x1,26); tf_round(x0,x1, 6);
  x0 += k1; x1 += k2 + 1u;
  tf_round(x0,x1,17); tf_round(x0,x1,29); tf_round(x0,x1,16); tf_round(x0,x1,24);
  x0 += k2; x1 += k0 + 2u;
  tf_round(x0,x1,13); tf_round(x0,x1,15); tf_round(x0,x1,26); tf_round(x0,x1, 6);
  x0 += k0; x1 += k1 + 3u;
  tf_round(x0,x1,17); tf_round(x0,x1,29); tf_round(x0,x1,16); tf_round(x0,x1,24);
  x0 += k1; x1 += k2 + 4u;
  tf_round(x0,x1,13); tf_round(x0,x1,15); tf_round(x0,x1,26); tf_round(x0,x1, 6);
  x0 += k2; x1 += k0 + 5u;
  o0 = x0; o1 = x1;
}

// XLA ErfInv32 (Giles polynomial) — matches jax.lax.erf_inv f32 path
static __device__ float erfinv32(float x){
  float w = -log1pf(-x * x);
  float p;
  if (w < 5.0f){
    w -= 2.5f;
    p = 2.81022636e-08f;
    p = fmaf(p, w, 3.43273939e-07f);
    p = fmaf(p, w, -3.5233877e-06f);
    p = fmaf(p, w, -4.39150654e-06f);
    p = fmaf(p, w, 0.00021858087f);
    p = fmaf(p, w, -0.00125372503f);
    p = fmaf(p, w, -0.00417768164f);
    p = fmaf(p, w, 0.246640727f);
    p = fmaf(p, w, 1.50140941f);
  } else {
    w = sqrtf(w) - 3.0f;
    p = -0.000200214257f;
    p = fmaf(p, w, 0.000100950558f);
    p = fmaf(p, w, 0.00134934322f);
    p = fmaf(p, w, -0.00367342844f);
    p = fmaf(p, w, 0.00573950773f);
    p = fmaf(p, w, -0.0076224613f);
    p = fmaf(p, w, 0.00943887047f);
    p = fmaf(p, w, 1.00167406f);
    p = fmaf(p, w, 2.83297682f);
  }
  return p * x;
}

static __device__ float bits_to_normal(unsigned b){
  // jax uniform: bitcast-mantissa trick into [0,1), affine to (lo, 1), clamp, then sqrt(2)*erfinv
  float f = __builtin_bit_cast(float, (b >> 9) | 0x3f800000u) - 1.0f;
  const float lo = -0x1.fffffep-1f;            // nextafterf(-1, 0)
  float u = f * (1.0f - lo) + lo;
  u = fmaxf(lo, u);
  return 1.4142135381698608f * erfinv32(u);
}

__global__ __launch_bounds__(NT) void sketch_kernel(
    const float* __restrict__ Wih, const float* __restrict__ bih,
    const float* __restrict__ bhh, const float* __restrict__ Wlin,
    const float* __restrict__ blin, float* __restrict__ out)
{
  __shared__ float EPS[2 * MAXS];   // flat (1000,2) row-major: eps[i][c] = EPS[2i+c]
  __shared__ float P[NWAVE * 8];
  __shared__ float LB[8];

  const int t    = threadIdx.x;
  const int lane = t & 63;
  const int wv   = t >> 6;

  // ---- init output: pad rows [0,0,0,0,1], row 0 = [0,0,1,0,0] ----
  for (int idx = t; idx < 5 * MAXS; idx += NT){
    int c = idx % 5;
    float v = (c == 4) ? 1.0f : 0.0f;
    if (idx == 2) v = 1.0f;
    else if (idx == 4) v = 0.0f;
    out[idx] = v;
  }

  // ---- eps via partitionable threefry: counter (0, flat_idx), fold o0^o1 ----
  for (int e = t; e < 2 * MAXS; e += NT){
    unsigned o0, o1;
    threefry2x32_0_42(0u, (unsigned)e, o0, o1);
    EPS[e] = bits_to_normal(o0 ^ o1);
  }

  // ---- preload weights into registers (log2e pre-scaled) ----
  const float L2E  = 1.4426950408889634f;
  const float L2E2 = 2.8853900817779268f;
  const int j = t * 4;  // 4 h-elements per thread: j..j+3

  v2f wig[2][5], wgg[2][5], wog[2][5];
  v2f big[2], bgg[2], bog[2];
  v2f wl[7][2];

  #pragma unroll
  for (int p = 0; p < 2; p++){
    const int r0 = j + 2*p, r1 = j + 2*p + 1;
    #pragma unroll
    for (int c = 0; c < 5; c++){
      v2f a; a.x = Wih[r0*5 + c];            a.y = Wih[r1*5 + c];            wig[p][c] = a * L2E;
      v2f g; g.x = Wih[(2*HH + r0)*5 + c];   g.y = Wih[(2*HH + r1)*5 + c];   wgg[p][c] = g * L2E2;
      v2f o; o.x = Wih[(3*HH + r0)*5 + c];   o.y = Wih[(3*HH + r1)*5 + c];   wog[p][c] = o * L2E;
    }
    v2f bi; bi.x = bih[r0] + bhh[r0];                   bi.y = bih[r1] + bhh[r1];                   big[p] = bi * L2E;
    v2f bg; bg.x = bih[2*HH + r0] + bhh[2*HH + r0];     bg.y = bih[2*HH + r1] + bhh[2*HH + r1];     bgg[p] = bg * L2E2;
    v2f bo; bo.x = bih[3*HH + r0] + bhh[3*HH + r0];     bo.y = bih[3*HH + r1] + bhh[3*HH + r1];     bog[p] = bo * L2E;
    #pragma unroll
    for (int k = 0; k < 7; k++){
      v2f wk; wk.x = Wlin[k*HH + r0]; wk.y = Wlin[k*HH + r1]; wl[k][p] = wk;
    }
  }
  const float bl = (wv == 0 && lane < 7) ? blin[lane] : 0.0f;

  __syncthreads();

  // carried state: last = init_row [0,0,1,0,0]
  float l0 = 0.f, l1 = 0.f, l2 = 1.f, l3 = 0.f, l4 = 0.f;

  for (int i = 1; i < MAXS; i++){
    // ---- gates + nonlinearities for this thread's 4 h-elements ----
    v2f hv[2];
    #pragma unroll
    for (int p = 0; p < 2; p++){
      v2f ig = big[p] + wig[p][0]*l0 + wig[p][1]*l1 + wig[p][2]*l2 + wig[p][3]*l3 + wig[p][4]*l4;
      v2f gg = bgg[p] + wgg[p][0]*l0 + wgg[p][1]*l1 + wgg[p][2]*l2 + wgg[p][3]*l3 + wgg[p][4]*l4;
      v2f og = bog[p] + wog[p][0]*l0 + wog[p][1]*l1 + wog[p][2]*l2 + wog[p][3]*l3 + wog[p][4]*l4;
      v2f si = sigm_s(ig);          // sigmoid(i-gate)
      v2f tg = tanh_s(gg);          // tanh(g-gate)
      v2f cs = (si * tg) * L2E2;    // c, pre-scaled for tanh
      v2f th = tanh_s(cs);          // tanh(c)
      v2f so = sigm_s(og);          // sigmoid(o-gate)
      hv[p] = so * th;              // h
    }

    // ---- 7 dot partials + in-wave DPP reduction ----
    float s[7];
    #pragma unroll
    for (int k = 0; k < 7; k++){
      v2f a = wl[k][0]*hv[0] + wl[k][1]*hv[1];
      s[k] = wave_sum63(a.x + a.y);
    }
    if (lane == 63){
      #pragma unroll
      for (int k = 0; k < 7; k++) P[wv*8 + k] = s[k];
    }
    __syncthreads();

    // ---- cross-wave combine + scalar epilogue on wave 0 ----
    if (wv == 0){
      float sum = 0.0f;
      if (lane < 7){
        #pragma unroll
        for (int q = 0; q < NWAVE; q++) sum += P[q*8 + lane];
      }
      float eo = exp2g((sum + bl) * L2E2);
      float o  = 1.0f - 2.0f * rcpg(1.0f + eo);     // out7[lane] = tanh(dot + b_lin)
      float o0 = __shfl(o, 0, 64), o1 = __shfl(o, 1, 64), o2 = __shfl(o, 2, 64),
            o3 = __shfl(o, 3, 64), o4 = __shfl(o, 4, 64), o5 = __shfl(o, 5, 64),
            o6 = __shfl(o, 6, 64);
      float eps0 = EPS[2*i], eps1 = EPS[2*i + 1];
      float sigx = exp2g(o1 * 0.7213475204444817f);  // exp(0.5*o1)
      float sigy = exp2g(o3 * 0.7213475204444817f);
      float m  = fmaxf(o4, fmaxf(o5, o6));
      float e4 = exp2g((o4 - m) * L2E), e5 = exp2g((o5 - m) * L2E), e6 = exp2g((o6 - m) * L2E);
      float rs = rcpg(e4 + e5 + e6);
      float p4 = e4*rs, p5 = e5*rs, p6 = e6*rs;
      float sx = fmaf(sigx, eps0, o0);
      float sy = fmaf(sigy, eps1, o2);
      // argmax(new_row[2:]) == 2  <=>  o6 strictly greatest (exp/softmax monotone)
      int dn = (o6 > o4) && (o6 > o5);
      float val = (lane == 0) ? sx : (lane == 1) ? sy : (lane == 2) ? p4 : (lane == 3) ? p5 : p6;
      if (lane < 5) out[i*5 + lane] = val;
      if (lane < 6) LB[lane] = (lane < 5) ? val : (dn ? 1.0f : 0.0f);
    }
    __syncthreads();

    // ---- broadcast carried state; uniform early-exit once pen-end fires ----
    l0 = rdfl(LB[0]); l1 = rdfl(LB[1]); l2 = rdfl(LB[2]); l3 = rdfl(LB[3]); l4 = rdfl(LB[4]);
    float df = LB[5];
    if (df != 0.0f) break;
  }
}

extern "C" void kernel_launch(void* const* d_in, const int* in_sizes, int n_in,
                              void* d_out, int out_size, void* d_ws, size_t ws_size,
                              hipStream_t stream) {
  const float* Wih  = (const float*)d_in[0];
  // d_in[1] = W_hh: dead (hidden state never propagated in the reference)
  const float* bih  = (const float*)d_in[2];
  const float* bhh  = (const float*)d_in[3];
  const float* Wlin = (const float*)d_in[4];
  const float* blin = (const float*)d_in[5];
  float* out = (float*)d_out;
  sketch_kernel<<<dim3(1), dim3(NT), 0, stream>>>(Wih, bih, bhh, Wlin, blin, out);
}

// Round 5
// 770.745 us; speedup vs baseline: 1.0582x; 1.0582x over previous
//
#include <hip/hip_runtime.h>

// SketchDecoder: sequential 1000-step scan, 5-float carried state.
// Ref bug: hidden state never propagated -> W_hh unused, fg gate unused.
// Single block, 512 threads (8 waves); weights in registers.
// RNG: JAX partitionable threefry: bits[i] = o0^o1 of threefry2x32((0,42),(0,i)).
// Step structure: ONE barrier/step; double-buffered 64-slot partial array;
// all waves redundantly compute the epilogue from readlane broadcasts.
// R4 bug: used row_ror:4 (dest i <- src i-4 mod 16) which crossed k-group
// boundaries. Correct op is row_shl:4 (dest i <- src i+4), mirroring the
// verified row_shr direction in wave_sum63.

typedef float v2f __attribute__((ext_vector_type(2)));

#define HH   2048
#define MAXS 1000
#define NT   512
#define NWAVE (NT / 64)

static __device__ __forceinline__ float exp2g(float x){ return __builtin_amdgcn_exp2f(x); }
static __device__ __forceinline__ float rcpg (float x){ return __builtin_amdgcn_rcpf(x); }
static __device__ __forceinline__ v2f exp2v(v2f x){ v2f r; r.x = exp2g(x.x); r.y = exp2g(x.y); return r; }
static __device__ __forceinline__ v2f rcpv (v2f x){ v2f r; r.x = rcpg(x.x); r.y = rcpg(x.y); return r; }

template<int CTRL>
static __device__ __forceinline__ float dpp_add(float x){
  int t = __builtin_amdgcn_update_dpp(0, __builtin_bit_cast(int, x), CTRL, 0xF, 0xF, true);
  return x + __builtin_bit_cast(float, t);
}
static __device__ __forceinline__ float wave_sum63(float x){
  x = dpp_add<0x111>(x);  // row_shr:1
  x = dpp_add<0x112>(x);  // row_shr:2
  x = dpp_add<0x114>(x);  // row_shr:4
  x = dpp_add<0x118>(x);  // row_shr:8
  x = dpp_add<0x142>(x);  // row_bcast:15
  x = dpp_add<0x143>(x);  // row_bcast:31 -> lane 63 = wave total
  return x;
}
static __device__ __forceinline__ float rdlane(float x, int l){
  return __builtin_bit_cast(float, __builtin_amdgcn_readlane(__builtin_bit_cast(int, x), l));
}

// ---- JAX threefry2x32, key (0, 42) ----
static __device__ __forceinline__ void tf_round(unsigned &x0, unsigned &x1, const int r){
  x0 += x1;
  x1 = (x1 << r) | (x1 >> (32 - r));
  x1 ^= x0;
}
static __device__ void threefry2x32_0_42(unsigned c0, unsigned c1, unsigned &o0, unsigned &o1){
  const unsigned k0 = 0u, k1 = 42u;
  const unsigned k2 = 0x1BD11BDAu ^ k0 ^ k1;
  unsigned x0 = c0 + k0, x1 = c1 + k1;
  tf_round(x0,x1,13); tf_round(x0,x1,15); tf_round(x0,x1,26); tf_round(x0,x1, 6);
  x0 += k1; x1 += k2 + 1u;
  tf_round(x0,x1,17); tf_round(x0,x1,29); tf_round(x0,x1,16); tf_round(x0,x1,24);
  x0 += k2; x1 += k0 + 2u;
  tf_round(x0,x1,13); tf_round(x0,x1,15); tf_round(x0,x1,26); tf_round(x0,x1, 6);
  x0 += k0; x1 += k1 + 3u;
  tf_round(x0,x1,17); tf_round(x0,x1,29); tf_round(x0,x1,16); tf_round(x0,x1,24);
  x0 += k1; x1 += k2 + 4u;
  tf_round(x0,x1,13); tf_round(x0,x1,15); tf_round(x0,x1,26); tf_round(x0,x1, 6);
  x0 += k2; x1 += k0 + 5u;
  o0 = x0; o1 = x1;
}

// XLA ErfInv32 (Giles polynomial)
static __device__ float erfinv32(float x){
  float w = -log1pf(-x * x);
  float p;
  if (w < 5.0f){
    w -= 2.5f;
    p = 2.81022636e-08f;
    p = fmaf(p, w, 3.43273939e-07f);
    p = fmaf(p, w, -3.5233877e-06f);
    p = fmaf(p, w, -4.39150654e-06f);
    p = fmaf(p, w, 0.00021858087f);
    p = fmaf(p, w, -0.00125372503f);
    p = fmaf(p, w, -0.00417768164f);
    p = fmaf(p, w, 0.246640727f);
    p = fmaf(p, w, 1.50140941f);
  } else {
    w = sqrtf(w) - 3.0f;
    p = -0.000200214257f;
    p = fmaf(p, w, 0.000100950558f);
    p = fmaf(p, w, 0.00134934322f);
    p = fmaf(p, w, -0.00367342844f);
    p = fmaf(p, w, 0.00573950773f);
    p = fmaf(p, w, -0.0076224613f);
    p = fmaf(p, w, 0.00943887047f);
    p = fmaf(p, w, 1.00167406f);
    p = fmaf(p, w, 2.83297682f);
  }
  return p * x;
}

static __device__ float bits_to_normal(unsigned b){
  float f = __builtin_bit_cast(float, (b >> 9) | 0x3f800000u) - 1.0f;
  const float lo = -0x1.fffffep-1f;
  float u = f * (1.0f - lo) + lo;
  u = fmaxf(lo, u);
  return 1.4142135381698608f * erfinv32(u);
}

__global__ __launch_bounds__(NT) void sketch_kernel(
    const float* __restrict__ Wih, const float* __restrict__ bih,
    const float* __restrict__ bhh, const float* __restrict__ Wlin,
    const float* __restrict__ blin, float* __restrict__ out)
{
  __shared__ float EPS[2 * MAXS];
  __shared__ float PB[2][64];   // [parity][k*8 + wave], k=0..6 used, row 7 stays 0

  const int t    = threadIdx.x;
  const int lane = t & 63;
  const int wv   = t >> 6;

  // ---- init output: pad rows [0,0,0,0,1], row 0 = [0,0,1,0,0] ----
  for (int idx = t; idx < 5 * MAXS; idx += NT){
    int c = idx % 5;
    float v = (c == 4) ? 1.0f : 0.0f;
    if (idx == 2) v = 1.0f;
    else if (idx == 4) v = 0.0f;
    out[idx] = v;
  }

  // ---- eps via partitionable threefry ----
  for (int e = t; e < 2 * MAXS; e += NT){
    unsigned o0, o1;
    threefry2x32_0_42(0u, (unsigned)e, o0, o1);
    EPS[e] = bits_to_normal(o0 ^ o1);
  }
  if (t < 128) ((float*)PB)[t] = 0.0f;

  // ---- preload weights into registers (log2e pre-scaled) ----
  const float L2E  = 1.4426950408889634f;
  const float L2E2 = 2.8853900817779268f;
  const int j = t * 4;

  v2f wig[2][5], wgg[2][5], wog[2][5];
  v2f big[2], bgg[2], bog[2];
  v2f wl[7][2];

  #pragma unroll
  for (int p = 0; p < 2; p++){
    const int r0 = j + 2*p, r1 = j + 2*p + 1;
    #pragma unroll
    for (int c = 0; c < 5; c++){
      v2f a; a.x = Wih[r0*5 + c];            a.y = Wih[r1*5 + c];            wig[p][c] = a * L2E;
      v2f g; g.x = Wih[(2*HH + r0)*5 + c];   g.y = Wih[(2*HH + r1)*5 + c];   wgg[p][c] = g * L2E2;
      v2f o; o.x = Wih[(3*HH + r0)*5 + c];   o.y = Wih[(3*HH + r1)*5 + c];   wog[p][c] = o * L2E;
    }
    v2f bi; bi.x = bih[r0] + bhh[r0];                   bi.y = bih[r1] + bhh[r1];                   big[p] = bi * L2E;
    v2f bg; bg.x = bih[2*HH + r0] + bhh[2*HH + r0];     bg.y = bih[2*HH + r1] + bhh[2*HH + r1];     bgg[p] = bg * L2E2;
    v2f bo; bo.x = bih[3*HH + r0] + bhh[3*HH + r0];     bo.y = bih[3*HH + r1] + bhh[3*HH + r1];     bog[p] = bo * L2E;
    #pragma unroll
    for (int k = 0; k < 7; k++){
      v2f wk; wk.x = Wlin[k*HH + r0]; wk.y = Wlin[k*HH + r1]; wl[k][p] = wk;
    }
  }
  const int kg = lane >> 3;                       // this lane's k-group for the epilogue
  const float blv = (kg < 7) ? blin[kg] : 0.0f;

  __syncthreads();

  // carried state (redundant on every lane): last = [0,0,1,0,0]
  float l0 = 0.f, l1 = 0.f, l2 = 1.f, l3 = 0.f, l4 = 0.f;
  int par = 0;

  for (int i = 1; i < MAXS; i++){
    float eps0 = EPS[2*i], eps1 = EPS[2*i + 1];   // prefetch, waited in epilogue

    // ---- gates + h, merged-rcp form: 6 trans/elem ----
    v2f hv[2];
    #pragma unroll
    for (int p = 0; p < 2; p++){
      v2f ig = big[p] + wig[p][0]*l0 + wig[p][1]*l1 + wig[p][2]*l2 + wig[p][3]*l3 + wig[p][4]*l4;
      v2f gg = bgg[p] + wgg[p][0]*l0 + wgg[p][1]*l1 + wgg[p][2]*l2 + wgg[p][3]*l3 + wgg[p][4]*l4;
      v2f og = bog[p] + wog[p][0]*l0 + wog[p][1]*l1 + wog[p][2]*l2 + wog[p][3]*l3 + wog[p][4]*l4;
      v2f a  = exp2v(-ig);                       // e^{-ig}
      v2f b  = exp2v(gg);                        // e^{2*gg}
      v2f r1 = rcpv((1.0f + a) * (1.0f + b));
      v2f st2 = (b * L2E2 - L2E2) * r1;          // c * 2*log2(e),  c = sig(ig)*tanh(gg)
      v2f d  = exp2v(st2);                       // e^{2c}
      v2f ao = exp2v(-og);                       // e^{-og}
      v2f r2 = rcpv((1.0f + ao) * (1.0f + d));
      hv[p] = (d - 1.0f) * r2;                   // sig(og)*tanh(c)
    }

    // ---- 7 dot partials + in-wave DPP reduction; lane 63 stores to PB ----
    #pragma unroll
    for (int k = 0; k < 7; k++){
      v2f a = wl[k][0]*hv[0] + wl[k][1]*hv[1];
      float s = wave_sum63(a.x + a.y);
      if (lane == 63) PB[par][k*8 + wv] = s;
    }
    __syncthreads();

    // ---- cross-wave butterfly over the 8 wave-partials (groups of 8 lanes) ----
    float v = PB[par][lane];
    par ^= 1;
    v = dpp_add<0xB1>(v);    // quad_perm [1,0,3,2]  (^1)
    v = dpp_add<0x4E>(v);    // quad_perm [2,3,0,1]  (^2)
    v = dpp_add<0x104>(v);   // row_shl:4 — dest i <- src i+4 (valid at row-lanes 0..11)
    // o_k on lanes 8k: tanh(s_k + b_lin[k])
    float o = 1.0f - 2.0f * rcpg(1.0f + exp2g((v + blv) * L2E2));
    float o0 = rdlane(o, 0),  o1 = rdlane(o, 8),  o2 = rdlane(o, 16),
          o3 = rdlane(o, 24), o4 = rdlane(o, 32), o5 = rdlane(o, 40),
          o6 = rdlane(o, 48);

    // ---- epilogue, redundant on every lane ----
    float sigx = exp2g(o1 * 0.7213475204444817f);
    float sigy = exp2g(o3 * 0.7213475204444817f);
    float m  = fmaxf(o4, fmaxf(o5, o6));
    float e4 = exp2g((o4 - m) * L2E), e5 = exp2g((o5 - m) * L2E), e6 = exp2g((o6 - m) * L2E);
    float rs = rcpg(e4 + e5 + e6);
    float p4 = e4*rs, p5 = e5*rs, p6 = e6*rs;
    float sx = fmaf(sigx, eps0, o0);
    float sy = fmaf(sigy, eps1, o2);
    bool dn = (o6 > o4) && (o6 > o5);

    if (t < 5){
      float val = (t == 0) ? sx : (t == 1) ? sy : (t == 2) ? p4 : (t == 3) ? p5 : p6;
      out[i*5 + t] = val;
    }
    l0 = sx; l1 = sy; l2 = p4; l3 = p5; l4 = p6;
    if (dn) break;   // block-uniform: all waves computed identical o's
  }
}

extern "C" void kernel_launch(void* const* d_in, const int* in_sizes, int n_in,
                              void* d_out, int out_size, void* d_ws, size_t ws_size,
                              hipStream_t stream) {
  const float* Wih  = (const float*)d_in[0];
  // d_in[1] = W_hh: dead (hidden state never propagated in the reference)
  const float* bih  = (const float*)d_in[2];
  const float* bhh  = (const float*)d_in[3];
  const float* Wlin = (const float*)d_in[4];
  const float* blin = (const float*)d_in[5];
  float* out = (float*)d_out;
  sketch_kernel<<<dim3(1), dim3(NT), 0, stream>>>(Wih, bih, bhh, Wlin, blin, out);
}

// Round 6
// 759.824 us; speedup vs baseline: 1.0734x; 1.0144x over previous
//
#include <hip/hip_runtime.h>

// SketchDecoder: sequential 1000-step scan, 5-float carried state.
// Ref bug: hidden state never propagated -> W_hh unused, fg gate unused.
// R6: 256 threads (4 waves, 1/SIMD), 8 h-elems/thread. Rationale: VALU
// issue-bound (R5: 67% busy on active CU); reduction(42 DPP)+epilogue are
// per-wave costs, so halving wave count halves that overhead while the
// data-parallel gate/dot work is conserved. launch_bounds(256,1) unlocks
// the full VGPR budget (~280 needed for register-resident weights).
// RNG: JAX partitionable threefry: bits[i] = o0^o1 of threefry2x32((0,42),(0,i)).

typedef float v2f __attribute__((ext_vector_type(2)));

#define HH   2048
#define MAXS 1000
#define NT   256
#define NWAVE (NT / 64)
#define EPT  4              // v2f pairs per thread (8 floats)

static __device__ __forceinline__ float exp2g(float x){ return __builtin_amdgcn_exp2f(x); }
static __device__ __forceinline__ float rcpg (float x){ return __builtin_amdgcn_rcpf(x); }
static __device__ __forceinline__ v2f exp2v(v2f x){ v2f r; r.x = exp2g(x.x); r.y = exp2g(x.y); return r; }
static __device__ __forceinline__ v2f rcpv (v2f x){ v2f r; r.x = rcpg(x.x); r.y = rcpg(x.y); return r; }

template<int CTRL>
static __device__ __forceinline__ float dpp_add(float x){
  int t = __builtin_amdgcn_update_dpp(0, __builtin_bit_cast(int, x), CTRL, 0xF, 0xF, true);
  return x + __builtin_bit_cast(float, t);
}
static __device__ __forceinline__ float wave_sum63(float x){
  x = dpp_add<0x111>(x);  // row_shr:1
  x = dpp_add<0x112>(x);  // row_shr:2
  x = dpp_add<0x114>(x);  // row_shr:4
  x = dpp_add<0x118>(x);  // row_shr:8
  x = dpp_add<0x142>(x);  // row_bcast:15
  x = dpp_add<0x143>(x);  // row_bcast:31 -> lane 63 = wave total
  return x;
}
static __device__ __forceinline__ float rdlane(float x, int l){
  return __builtin_bit_cast(float, __builtin_amdgcn_readlane(__builtin_bit_cast(int, x), l));
}

// ---- JAX threefry2x32, key (0, 42) ----
static __device__ __forceinline__ void tf_round(unsigned &x0, unsigned &x1, const int r){
  x0 += x1;
  x1 = (x1 << r) | (x1 >> (32 - r));
  x1 ^= x0;
}
static __device__ void threefry2x32_0_42(unsigned c0, unsigned c1, unsigned &o0, unsigned &o1){
  const unsigned k0 = 0u, k1 = 42u;
  const unsigned k2 = 0x1BD11BDAu ^ k0 ^ k1;
  unsigned x0 = c0 + k0, x1 = c1 + k1;
  tf_round(x0,x1,13); tf_round(x0,x1,15); tf_round(x0,x1,26); tf_round(x0,x1, 6);
  x0 += k1; x1 += k2 + 1u;
  tf_round(x0,x1,17); tf_round(x0,x1,29); tf_round(x0,x1,16); tf_round(x0,x1,24);
  x0 += k2; x1 += k0 + 2u;
  tf_round(x0,x1,13); tf_round(x0,x1,15); tf_round(x0,x1,26); tf_round(x0,x1, 6);
  x0 += k0; x1 += k1 + 3u;
  tf_round(x0,x1,17); tf_round(x0,x1,29); tf_round(x0,x1,16); tf_round(x0,x1,24);
  x0 += k1; x1 += k2 + 4u;
  tf_round(x0,x1,13); tf_round(x0,x1,15); tf_round(x0,x1,26); tf_round(x0,x1, 6);
  x0 += k2; x1 += k0 + 5u;
  o0 = x0; o1 = x1;
}

// XLA ErfInv32 (Giles polynomial)
static __device__ float erfinv32(float x){
  float w = -log1pf(-x * x);
  float p;
  if (w < 5.0f){
    w -= 2.5f;
    p = 2.81022636e-08f;
    p = fmaf(p, w, 3.43273939e-07f);
    p = fmaf(p, w, -3.5233877e-06f);
    p = fmaf(p, w, -4.39150654e-06f);
    p = fmaf(p, w, 0.00021858087f);
    p = fmaf(p, w, -0.00125372503f);
    p = fmaf(p, w, -0.00417768164f);
    p = fmaf(p, w, 0.246640727f);
    p = fmaf(p, w, 1.50140941f);
  } else {
    w = sqrtf(w) - 3.0f;
    p = -0.000200214257f;
    p = fmaf(p, w, 0.000100950558f);
    p = fmaf(p, w, 0.00134934322f);
    p = fmaf(p, w, -0.00367342844f);
    p = fmaf(p, w, 0.00573950773f);
    p = fmaf(p, w, -0.0076224613f);
    p = fmaf(p, w, 0.00943887047f);
    p = fmaf(p, w, 1.00167406f);
    p = fmaf(p, w, 2.83297682f);
  }
  return p * x;
}

static __device__ float bits_to_normal(unsigned b){
  float f = __builtin_bit_cast(float, (b >> 9) | 0x3f800000u) - 1.0f;
  const float lo = -0x1.fffffep-1f;
  float u = f * (1.0f - lo) + lo;
  u = fmaxf(lo, u);
  return 1.4142135381698608f * erfinv32(u);
}

__global__ __launch_bounds__(NT, 1) void sketch_kernel(
    const float* __restrict__ Wih, const float* __restrict__ bih,
    const float* __restrict__ bhh, const float* __restrict__ Wlin,
    const float* __restrict__ blin, float* __restrict__ out)
{
  __shared__ float EPS[2 * MAXS];
  __shared__ float PB[2][64];   // [parity][k*4 + wave], k=0..6 used; rest stays 0

  const int t    = threadIdx.x;
  const int lane = t & 63;
  const int wv   = t >> 6;

  // ---- init output: pad rows [0,0,0,0,1], row 0 = [0,0,1,0,0] ----
  for (int idx = t; idx < 5 * MAXS; idx += NT){
    int c = idx % 5;
    float v = (c == 4) ? 1.0f : 0.0f;
    if (idx == 2) v = 1.0f;
    else if (idx == 4) v = 0.0f;
    out[idx] = v;
  }

  // ---- eps via partitionable threefry ----
  for (int e = t; e < 2 * MAXS; e += NT){
    unsigned o0, o1;
    threefry2x32_0_42(0u, (unsigned)e, o0, o1);
    EPS[e] = bits_to_normal(o0 ^ o1);
  }
  if (t < 128) ((float*)PB)[t] = 0.0f;

  // ---- preload weights into registers (log2e pre-scaled) ----
  const float L2E  = 1.4426950408889634f;
  const float L2E2 = 2.8853900817779268f;
  const int j = t * (2 * EPT);   // 8 h-elements per thread: j..j+7

  v2f wig[EPT][5], wgg[EPT][5], wog[EPT][5];
  v2f big[EPT], bgg[EPT], bog[EPT];
  v2f wl[7][EPT];

  #pragma unroll
  for (int p = 0; p < EPT; p++){
    const int r0 = j + 2*p, r1 = j + 2*p + 1;
    #pragma unroll
    for (int c = 0; c < 5; c++){
      v2f a; a.x = Wih[r0*5 + c];            a.y = Wih[r1*5 + c];            wig[p][c] = a * L2E;
      v2f g; g.x = Wih[(2*HH + r0)*5 + c];   g.y = Wih[(2*HH + r1)*5 + c];   wgg[p][c] = g * L2E2;
      v2f o; o.x = Wih[(3*HH + r0)*5 + c];   o.y = Wih[(3*HH + r1)*5 + c];   wog[p][c] = o * L2E;
    }
    v2f bi; bi.x = bih[r0] + bhh[r0];                   bi.y = bih[r1] + bhh[r1];                   big[p] = bi * L2E;
    v2f bg; bg.x = bih[2*HH + r0] + bhh[2*HH + r0];     bg.y = bih[2*HH + r1] + bhh[2*HH + r1];     bgg[p] = bg * L2E2;
    v2f bo; bo.x = bih[3*HH + r0] + bhh[3*HH + r0];     bo.y = bih[3*HH + r1] + bhh[3*HH + r1];     bog[p] = bo * L2E;
    #pragma unroll
    for (int k = 0; k < 7; k++){
      v2f wk; wk.x = Wlin[k*HH + r0]; wk.y = Wlin[k*HH + r1]; wl[k][p] = wk;
    }
  }
  const int kq = lane >> 2;                       // this lane's k-quad for the epilogue
  const float blv = (kq < 7) ? blin[kq] : 0.0f;

  __syncthreads();

  // carried state (redundant on every lane): last = [0,0,1,0,0]
  float l0 = 0.f, l1 = 0.f, l2 = 1.f, l3 = 0.f, l4 = 0.f;
  int par = 0;

  for (int i = 1; i < MAXS; i++){
    float eps0 = EPS[2*i], eps1 = EPS[2*i + 1];   // prefetch, waited in epilogue

    // ---- gates + h, merged-rcp form: 6 trans/elem ----
    v2f hv[EPT];
    #pragma unroll
    for (int p = 0; p < EPT; p++){
      v2f ig = big[p] + wig[p][0]*l0 + wig[p][1]*l1 + wig[p][2]*l2 + wig[p][3]*l3 + wig[p][4]*l4;
      v2f gg = bgg[p] + wgg[p][0]*l0 + wgg[p][1]*l1 + wgg[p][2]*l2 + wgg[p][3]*l3 + wgg[p][4]*l4;
      v2f og = bog[p] + wog[p][0]*l0 + wog[p][1]*l1 + wog[p][2]*l2 + wog[p][3]*l3 + wog[p][4]*l4;
      v2f a  = exp2v(-ig);                       // e^{-ig}
      v2f b  = exp2v(gg);                        // e^{2*gg}
      v2f r1 = rcpv((1.0f + a) * (1.0f + b));
      v2f st2 = (b * L2E2 - L2E2) * r1;          // c * 2*log2(e),  c = sig(ig)*tanh(gg)
      v2f d  = exp2v(st2);                       // e^{2c}
      v2f ao = exp2v(-og);                       // e^{-og}
      v2f r2 = rcpv((1.0f + ao) * (1.0f + d));
      hv[p] = (d - 1.0f) * r2;                   // sig(og)*tanh(c)
    }

    // ---- 7 dot partials + in-wave DPP reduction; lane 63 stores to PB ----
    #pragma unroll
    for (int k = 0; k < 7; k++){
      v2f a = wl[k][0]*hv[0] + wl[k][1]*hv[1] + wl[k][2]*hv[2] + wl[k][3]*hv[3];
      float s = wave_sum63(a.x + a.y);
      if (lane == 63) PB[par][k*4 + wv] = s;
    }
    __syncthreads();

    // ---- cross-wave reduce over 4 wave-partials (aligned quads) ----
    float v = PB[par][lane];
    par ^= 1;
    v = dpp_add<0xB1>(v);    // quad_perm [1,0,3,2]  (^1)
    v = dpp_add<0x4E>(v);    // quad_perm [2,3,0,1]  (^2) -> every lane in quad k has total
    // o_k on lanes 4k: tanh(s_k + b_lin[k])
    float o = 1.0f - 2.0f * rcpg(1.0f + exp2g((v + blv) * L2E2));
    float o0 = rdlane(o, 0),  o1 = rdlane(o, 4),  o2 = rdlane(o, 8),
          o3 = rdlane(o, 12), o4 = rdlane(o, 16), o5 = rdlane(o, 20),
          o6 = rdlane(o, 24);

    // ---- epilogue, redundant on every lane ----
    float sigx = exp2g(o1 * 0.7213475204444817f);
    float sigy = exp2g(o3 * 0.7213475204444817f);
    float m  = fmaxf(o4, fmaxf(o5, o6));
    float e4 = exp2g((o4 - m) * L2E), e5 = exp2g((o5 - m) * L2E), e6 = exp2g((o6 - m) * L2E);
    float rs = rcpg(e4 + e5 + e6);
    float p4 = e4*rs, p5 = e5*rs, p6 = e6*rs;
    float sx = fmaf(sigx, eps0, o0);
    float sy = fmaf(sigy, eps1, o2);
    bool dn = (o6 > o4) && (o6 > o5);

    if (t < 5){
      float val = (t == 0) ? sx : (t == 1) ? sy : (t == 2) ? p4 : (t == 3) ? p5 : p6;
      out[i*5 + t] = val;
    }
    l0 = sx; l1 = sy; l2 = p4; l3 = p5; l4 = p6;
    if (dn) break;   // block-uniform: all waves computed identical o's
  }
}

extern "C" void kernel_launch(void* const* d_in, const int* in_sizes, int n_in,
                              void* d_out, int out_size, void* d_ws, size_t ws_size,
                              hipStream_t stream) {
  const float* Wih  = (const float*)d_in[0];
  // d_in[1] = W_hh: dead (hidden state never propagated in the reference)
  const float* bih  = (const float*)d_in[2];
  const float* bhh  = (const float*)d_in[3];
  const float* Wlin = (const float*)d_in[4];
  const float* blin = (const float*)d_in[5];
  float* out = (float*)d_out;
  sketch_kernel<<<dim3(1), dim3(NT), 0, stream>>>(Wih, bih, bhh, Wlin, blin, out);
}

// Round 7
// 749.666 us; speedup vs baseline: 1.0880x; 1.0136x over previous
//
#include <hip/hip_runtime.h>

// SketchDecoder: sequential 1000-step scan, 5-float carried state.
// Ref bug: hidden state never propagated -> W_hh unused, fg gate unused.
// R7: R6 structure (256 threads, 4 waves, 8 elems/thread) + weights PINNED
// into VGPRs via empty asm. R5/R6 evidence (VGPR_Count 68/120, dur flat at
// ~678 while issue count dropped 25%) => compiler was re-loading weights
// from L1/L2 every step; that load latency was the real bottleneck.
// RNG: JAX partitionable threefry: bits[i] = o0^o1 of threefry2x32((0,42),(0,i)).

typedef float v2f __attribute__((ext_vector_type(2)));

#define HH   2048
#define MAXS 1000
#define NT   256
#define NWAVE (NT / 64)
#define EPT  4              // v2f pairs per thread (8 floats)

static __device__ __forceinline__ float exp2g(float x){ return __builtin_amdgcn_exp2f(x); }
static __device__ __forceinline__ float rcpg (float x){ return __builtin_amdgcn_rcpf(x); }
static __device__ __forceinline__ v2f exp2v(v2f x){ v2f r; r.x = exp2g(x.x); r.y = exp2g(x.y); return r; }
static __device__ __forceinline__ v2f rcpv (v2f x){ v2f r; r.x = rcpg(x.x); r.y = rcpg(x.y); return r; }

// Pin a value into a VGPR and make it opaque to the optimizer (prevents
// rematerialization of the originating global load inside the scan loop).
static __device__ __forceinline__ void pin(v2f &v){
  asm volatile("" : "+v"(v.x), "+v"(v.y));
}

template<int CTRL>
static __device__ __forceinline__ float dpp_add(float x){
  int t = __builtin_amdgcn_update_dpp(0, __builtin_bit_cast(int, x), CTRL, 0xF, 0xF, true);
  return x + __builtin_bit_cast(float, t);
}
static __device__ __forceinline__ float wave_sum63(float x){
  x = dpp_add<0x111>(x);  // row_shr:1
  x = dpp_add<0x112>(x);  // row_shr:2
  x = dpp_add<0x114>(x);  // row_shr:4
  x = dpp_add<0x118>(x);  // row_shr:8
  x = dpp_add<0x142>(x);  // row_bcast:15
  x = dpp_add<0x143>(x);  // row_bcast:31 -> lane 63 = wave total
  return x;
}
static __device__ __forceinline__ float rdlane(float x, int l){
  return __builtin_bit_cast(float, __builtin_amdgcn_readlane(__builtin_bit_cast(int, x), l));
}

// ---- JAX threefry2x32, key (0, 42) ----
static __device__ __forceinline__ void tf_round(unsigned &x0, unsigned &x1, const int r){
  x0 += x1;
  x1 = (x1 << r) | (x1 >> (32 - r));
  x1 ^= x0;
}
static __device__ void threefry2x32_0_42(unsigned c0, unsigned c1, unsigned &o0, unsigned &o1){
  const unsigned k0 = 0u, k1 = 42u;
  const unsigned k2 = 0x1BD11BDAu ^ k0 ^ k1;
  unsigned x0 = c0 + k0, x1 = c1 + k1;
  tf_round(x0,x1,13); tf_round(x0,x1,15); tf_round(x0,x1,26); tf_round(x0,x1, 6);
  x0 += k1; x1 += k2 + 1u;
  tf_round(x0,x1,17); tf_round(x0,x1,29); tf_round(x0,x1,16); tf_round(x0,x1,24);
  x0 += k2; x1 += k0 + 2u;
  tf_round(x0,x1,13); tf_round(x0,x1,15); tf_round(x0,x1,26); tf_round(x0,x1, 6);
  x0 += k0; x1 += k1 + 3u;
  tf_round(x0,x1,17); tf_round(x0,x1,29); tf_round(x0,x1,16); tf_round(x0,x1,24);
  x0 += k1; x1 += k2 + 4u;
  tf_round(x0,x1,13); tf_round(x0,x1,15); tf_round(x0,x1,26); tf_round(x0,x1, 6);
  x0 += k2; x1 += k0 + 5u;
  o0 = x0; o1 = x1;
}

// XLA ErfInv32 (Giles polynomial)
static __device__ float erfinv32(float x){
  float w = -log1pf(-x * x);
  float p;
  if (w < 5.0f){
    w -= 2.5f;
    p = 2.81022636e-08f;
    p = fmaf(p, w, 3.43273939e-07f);
    p = fmaf(p, w, -3.5233877e-06f);
    p = fmaf(p, w, -4.39150654e-06f);
    p = fmaf(p, w, 0.00021858087f);
    p = fmaf(p, w, -0.00125372503f);
    p = fmaf(p, w, -0.00417768164f);
    p = fmaf(p, w, 0.246640727f);
    p = fmaf(p, w, 1.50140941f);
  } else {
    w = sqrtf(w) - 3.0f;
    p = -0.000200214257f;
    p = fmaf(p, w, 0.000100950558f);
    p = fmaf(p, w, 0.00134934322f);
    p = fmaf(p, w, -0.00367342844f);
    p = fmaf(p, w, 0.00573950773f);
    p = fmaf(p, w, -0.0076224613f);
    p = fmaf(p, w, 0.00943887047f);
    p = fmaf(p, w, 1.00167406f);
    p = fmaf(p, w, 2.83297682f);
  }
  return p * x;
}

static __device__ float bits_to_normal(unsigned b){
  float f = __builtin_bit_cast(float, (b >> 9) | 0x3f800000u) - 1.0f;
  const float lo = -0x1.fffffep-1f;
  float u = f * (1.0f - lo) + lo;
  u = fmaxf(lo, u);
  return 1.4142135381698608f * erfinv32(u);
}

__global__ __launch_bounds__(NT, 1) void sketch_kernel(
    const float* __restrict__ Wih, const float* __restrict__ bih,
    const float* __restrict__ bhh, const float* __restrict__ Wlin,
    const float* __restrict__ blin, float* __restrict__ out)
{
  __shared__ float EPS[2 * MAXS];
  __shared__ float PB[2][64];   // [parity][k*4 + wave], k=0..6 used; rest stays 0

  const int t    = threadIdx.x;
  const int lane = t & 63;
  const int wv   = t >> 6;

  // ---- init output: pad rows [0,0,0,0,1], row 0 = [0,0,1,0,0] ----
  for (int idx = t; idx < 5 * MAXS; idx += NT){
    int c = idx % 5;
    float v = (c == 4) ? 1.0f : 0.0f;
    if (idx == 2) v = 1.0f;
    else if (idx == 4) v = 0.0f;
    out[idx] = v;
  }

  // ---- eps via partitionable threefry ----
  for (int e = t; e < 2 * MAXS; e += NT){
    unsigned o0, o1;
    threefry2x32_0_42(0u, (unsigned)e, o0, o1);
    EPS[e] = bits_to_normal(o0 ^ o1);
  }
  if (t < 128) ((float*)PB)[t] = 0.0f;

  // ---- preload weights into registers (log2e pre-scaled) ----
  const float L2E  = 1.4426950408889634f;
  const float L2E2 = 2.8853900817779268f;
  const int j = t * (2 * EPT);   // 8 h-elements per thread: j..j+7

  v2f wig[EPT][5], wgg[EPT][5], wog[EPT][5];
  v2f big[EPT], bgg[EPT], bog[EPT];
  v2f wl[7][EPT];

  #pragma unroll
  for (int p = 0; p < EPT; p++){
    const int r0 = j + 2*p, r1 = j + 2*p + 1;
    #pragma unroll
    for (int c = 0; c < 5; c++){
      v2f a; a.x = Wih[r0*5 + c];            a.y = Wih[r1*5 + c];            wig[p][c] = a * L2E;
      v2f g; g.x = Wih[(2*HH + r0)*5 + c];   g.y = Wih[(2*HH + r1)*5 + c];   wgg[p][c] = g * L2E2;
      v2f o; o.x = Wih[(3*HH + r0)*5 + c];   o.y = Wih[(3*HH + r1)*5 + c];   wog[p][c] = o * L2E;
    }
    v2f bi; bi.x = bih[r0] + bhh[r0];                   bi.y = bih[r1] + bhh[r1];                   big[p] = bi * L2E;
    v2f bg; bg.x = bih[2*HH + r0] + bhh[2*HH + r0];     bg.y = bih[2*HH + r1] + bhh[2*HH + r1];     bgg[p] = bg * L2E2;
    v2f bo; bo.x = bih[3*HH + r0] + bhh[3*HH + r0];     bo.y = bih[3*HH + r1] + bhh[3*HH + r1];     bog[p] = bo * L2E;
    #pragma unroll
    for (int k = 0; k < 7; k++){
      v2f wk; wk.x = Wlin[k*HH + r0]; wk.y = Wlin[k*HH + r1]; wl[k][p] = wk;
    }
  }

  // ---- pin all weights/biases into VGPRs (defeat load rematerialization) ----
  #pragma unroll
  for (int p = 0; p < EPT; p++){
    #pragma unroll
    for (int c = 0; c < 5; c++){ pin(wig[p][c]); pin(wgg[p][c]); pin(wog[p][c]); }
    pin(big[p]); pin(bgg[p]); pin(bog[p]);
    #pragma unroll
    for (int k = 0; k < 7; k++) pin(wl[k][p]);
  }

  const int kq = lane >> 2;                       // this lane's k-quad for the epilogue
  const float blv = (kq < 7) ? blin[kq] : 0.0f;

  __syncthreads();

  // carried state (redundant on every lane): last = [0,0,1,0,0]
  float l0 = 0.f, l1 = 0.f, l2 = 1.f, l3 = 0.f, l4 = 0.f;
  int par = 0;

  for (int i = 1; i < MAXS; i++){
    float eps0 = EPS[2*i], eps1 = EPS[2*i + 1];   // prefetch, waited in epilogue

    // ---- gates + h, merged-rcp form: 6 trans/elem ----
    v2f hv[EPT];
    #pragma unroll
    for (int p = 0; p < EPT; p++){
      v2f ig = big[p] + wig[p][0]*l0 + wig[p][1]*l1 + wig[p][2]*l2 + wig[p][3]*l3 + wig[p][4]*l4;
      v2f gg = bgg[p] + wgg[p][0]*l0 + wgg[p][1]*l1 + wgg[p][2]*l2 + wgg[p][3]*l3 + wgg[p][4]*l4;
      v2f og = bog[p] + wog[p][0]*l0 + wog[p][1]*l1 + wog[p][2]*l2 + wog[p][3]*l3 + wog[p][4]*l4;
      v2f a  = exp2v(-ig);                       // e^{-ig}
      v2f b  = exp2v(gg);                        // e^{2*gg}
      v2f r1 = rcpv((1.0f + a) * (1.0f + b));
      v2f st2 = (b * L2E2 - L2E2) * r1;          // c * 2*log2(e),  c = sig(ig)*tanh(gg)
      v2f d  = exp2v(st2);                       // e^{2c}
      v2f ao = exp2v(-og);                       // e^{-og}
      v2f r2 = rcpv((1.0f + ao) * (1.0f + d));
      hv[p] = (d - 1.0f) * r2;                   // sig(og)*tanh(c)
    }

    // ---- 7 dot partials + in-wave DPP reduction; lane 63 stores to PB ----
    #pragma unroll
    for (int k = 0; k < 7; k++){
      v2f a = wl[k][0]*hv[0] + wl[k][1]*hv[1] + wl[k][2]*hv[2] + wl[k][3]*hv[3];
      float s = wave_sum63(a.x + a.y);
      if (lane == 63) PB[par][k*4 + wv] = s;
    }
    __syncthreads();

    // ---- cross-wave reduce over 4 wave-partials (aligned quads) ----
    float v = PB[par][lane];
    par ^= 1;
    v = dpp_add<0xB1>(v);    // quad_perm [1,0,3,2]  (^1)
    v = dpp_add<0x4E>(v);    // quad_perm [2,3,0,1]  (^2) -> every lane in quad k has total
    // o_k on lanes 4k: tanh(s_k + b_lin[k])
    float o = 1.0f - 2.0f * rcpg(1.0f + exp2g((v + blv) * L2E2));
    float o0 = rdlane(o, 0),  o1 = rdlane(o, 4),  o2 = rdlane(o, 8),
          o3 = rdlane(o, 12), o4 = rdlane(o, 16), o5 = rdlane(o, 20),
          o6 = rdlane(o, 24);

    // ---- epilogue, redundant on every lane ----
    float sigx = exp2g(o1 * 0.7213475204444817f);
    float sigy = exp2g(o3 * 0.7213475204444817f);
    float m  = fmaxf(o4, fmaxf(o5, o6));
    float e4 = exp2g((o4 - m) * L2E), e5 = exp2g((o5 - m) * L2E), e6 = exp2g((o6 - m) * L2E);
    float rs = rcpg(e4 + e5 + e6);
    float p4 = e4*rs, p5 = e5*rs, p6 = e6*rs;
    float sx = fmaf(sigx, eps0, o0);
    float sy = fmaf(sigy, eps1, o2);
    bool dn = (o6 > o4) && (o6 > o5);

    if (t < 5){
      float val = (t == 0) ? sx : (t == 1) ? sy : (t == 2) ? p4 : (t == 3) ? p5 : p6;
      out[i*5 + t] = val;
    }
    l0 = sx; l1 = sy; l2 = p4; l3 = p5; l4 = p6;
    if (dn) break;   // block-uniform: all waves computed identical o's
  }
}

extern "C" void kernel_launch(void* const* d_in, const int* in_sizes, int n_in,
                              void* d_out, int out_size, void* d_ws, size_t ws_size,
                              hipStream_t stream) {
  const float* Wih  = (const float*)d_in[0];
  // d_in[1] = W_hh: dead (hidden state never propagated in the reference)
  const float* bih  = (const float*)d_in[2];
  const float* bhh  = (const float*)d_in[3];
  const float* Wlin = (const float*)d_in[4];
  const float* blin = (const float*)d_in[5];
  float* out = (float*)d_out;
  sketch_kernel<<<dim3(1), dim3(NT), 0, stream>>>(Wih, bih, bhh, Wlin, blin, out);
}